// Round 9
// baseline (61.302 us; speedup 1.0000x reference)
//
#include <hip/hip_runtime.h>

#define N_NODES  100000
#define N_EDGES  3200000
#define D_FEAT   128
#define SLICE    33344         // 3 slices cover 100000; 130.25 KiB LDS
#define SLICE4   (SLICE / 4)
#define N_SLICES 3
#define NCHUNK   80            // edge chunks; grid = 240 = 10 groups of 24
#define EPB      40000         // N_EDGES / NCHUNK; multiple of 8
#define TPB      1024
#define STRIDE   (TPB * 8)     // 8192 edges per iteration per block

__device__ __forceinline__ unsigned short f2bf(float f) {
    union { float f; unsigned u; } c; c.f = f;
    unsigned r = c.u + 0x7FFFu + ((c.u >> 16) & 1u);   // round-nearest-even
    return (unsigned short)(r >> 16);
}
__device__ __forceinline__ float bf2f(unsigned short h) {
    union { unsigned u; float f; } c; c.u = ((unsigned)h) << 16; return c.f;
}

// ---------------------------------------------------------------------------
// Kernel 1: per-node feature row-sum. 32 lanes per row, float4 per lane.
// ---------------------------------------------------------------------------
__global__ void __launch_bounds__(256) rowsum_kernel(
    const float* __restrict__ feat,
    float* __restrict__ rowsum)
{
    const int gid = (int)(blockIdx.x * blockDim.x + threadIdx.x);
    const int row = gid >> 5;
    const int sub = gid & 31;
    if (row >= N_NODES) return;

    const float4 v = reinterpret_cast<const float4*>(
        feat + (size_t)row * D_FEAT)[sub];
    float s = (v.x + v.y) + (v.z + v.w);

    #pragma unroll
    for (int off = 16; off > 0; off >>= 1)
        s += __shfl_xor(s, off, 64);

    if (sub == 0) rowsum[row] = s;
}

// ---------------------------------------------------------------------------
// Kernel 2 (phase 1): materialize edge values. val[e] = bf16(rowsum[src[e]]).
// Every lane active; each edge gathered EXACTLY once (no per-slice masked
// replication of divergent gathers). No LDS -> max occupancy; TA saturated
// chip-wide. 3125 blocks x 256 threads x 4 edges tiles N_EDGES exactly.
// ---------------------------------------------------------------------------
__global__ void __launch_bounds__(256) gather_kernel(
    const int* __restrict__ edge_src,
    const float* __restrict__ rowsum,
    unsigned short* __restrict__ val)
{
    const int e = ((int)(blockIdx.x * 256 + threadIdx.x)) * 4;
    const int4 s4 = *reinterpret_cast<const int4*>(edge_src + e);
    ushort4 o;
    o.x = f2bf(rowsum[s4.x]);
    o.y = f2bf(rowsum[s4.y]);
    o.z = f2bf(rowsum[s4.z]);
    o.w = f2bf(rowsum[s4.w]);
    *reinterpret_cast<ushort4*>(val + e) = o;
}

// ---------------------------------------------------------------------------
// Kernel 3 (phase 2): streaming scatter. Reads dst[] + val[] (NO random
// global loads at all), masked ds_add into the LDS slice, bf16 flush.
// XCD-sibling swizzle: bid = g*24 + tier*8 + xcd -> the 3 tier-siblings of
// a chunk share one XCD's L2 (dst/val fetched from HBM once).
// ---------------------------------------------------------------------------
__global__ void __launch_bounds__(TPB) scatter2_kernel(
    const int* __restrict__ edge_dst,
    const unsigned short* __restrict__ val,
    unsigned short* __restrict__ copies)
{
    __shared__ float lds[SLICE];

    const int tid = (int)threadIdx.x;
    const int bid = (int)blockIdx.x;
    const int g   = bid / 24;
    const int r   = bid % 24;
    const int xcd = r & 7;
    const int s   = r >> 3;               // slice (0..2)
    const int b   = g * 8 + xcd;          // chunk (0..79)
    const int lo  = s * SLICE;
    const unsigned len = (unsigned)((N_NODES - lo < SLICE) ? (N_NODES - lo) : SLICE);

    float4 z; z.x = z.y = z.z = z.w = 0.0f;
    for (int i = tid; i < SLICE4; i += TPB)
        reinterpret_cast<float4*>(lds)[i] = z;
    __syncthreads();

    const int begin = b * EPB;
    const int end   = begin + EPB;        // chunks tile N_EDGES exactly

    int e = begin + tid * 8;              // EPB % 8 == 0 -> one bool per group
    bool v = (e < end);

    int4    d0, d1;
    ushort4 w01;                          // 8 bf16 values
    ushort4 w23;
    if (v) {
        d0  = *(const int4*)(edge_dst + e);
        d1  = *(const int4*)(edge_dst + e + 4);
        w01 = *(const ushort4*)(val + e);
        w23 = *(const ushort4*)(val + e + 4);
    }

    while (v) {
        // prefetch next iteration
        const int en = e + STRIDE;
        const bool vn = (en < end);
        int4 nd0, nd1; ushort4 nw01, nw23;
        if (vn) {
            nd0  = *(const int4*)(edge_dst + en);
            nd1  = *(const int4*)(edge_dst + en + 4);
            nw01 = *(const ushort4*)(val + en);
            nw23 = *(const ushort4*)(val + en + 4);
        }

        const unsigned j0 = (unsigned)(d0.x - lo);
        const unsigned j1 = (unsigned)(d0.y - lo);
        const unsigned j2 = (unsigned)(d0.z - lo);
        const unsigned j3 = (unsigned)(d0.w - lo);
        const unsigned j4 = (unsigned)(d1.x - lo);
        const unsigned j5 = (unsigned)(d1.y - lo);
        const unsigned j6 = (unsigned)(d1.z - lo);
        const unsigned j7 = (unsigned)(d1.w - lo);

        if (j0 < len) atomicAdd(&lds[j0], bf2f(w01.x));
        if (j1 < len) atomicAdd(&lds[j1], bf2f(w01.y));
        if (j2 < len) atomicAdd(&lds[j2], bf2f(w01.z));
        if (j3 < len) atomicAdd(&lds[j3], bf2f(w01.w));
        if (j4 < len) atomicAdd(&lds[j4], bf2f(w23.x));
        if (j5 < len) atomicAdd(&lds[j5], bf2f(w23.y));
        if (j6 < len) atomicAdd(&lds[j6], bf2f(w23.z));
        if (j7 < len) atomicAdd(&lds[j7], bf2f(w23.w));

        e = en; v = vn;
        d0 = nd0; d1 = nd1; w01 = nw01; w23 = nw23;
    }
    __syncthreads();

    // flush LDS slice as bf16 partials
    unsigned short* __restrict__ dstp = copies + ((size_t)s * NCHUNK + b) * SLICE;
    const int len4 = (int)len >> 2;
    for (int i = tid; i < len4; i += TPB) {
        const float4 vv = reinterpret_cast<const float4*>(lds)[i];
        ushort4 o;
        o.x = f2bf(vv.x); o.y = f2bf(vv.y); o.z = f2bf(vv.z); o.w = f2bf(vv.w);
        reinterpret_cast<ushort4*>(dstp)[i] = o;
    }
}

// ---------------------------------------------------------------------------
// Kernel 4: reduce the NCHUNK bf16 copies per slice + activations + int cast.
// ---------------------------------------------------------------------------
__global__ void __launch_bounds__(256) reduce_final_kernel(
    const unsigned short* __restrict__ copies,
    int* __restrict__ out)
{
    const int i4 = (int)(blockIdx.x * blockDim.x + threadIdx.x);
    if (i4 >= N_NODES / 4) return;

    const int s  = (i4 >= 2 * SLICE4) ? 2 : (i4 >= SLICE4 ? 1 : 0);
    const int j4 = i4 - s * SLICE4;

    float ax = 0.0f, ay = 0.0f, az = 0.0f, aw = 0.0f;
    const ushort4* base = reinterpret_cast<const ushort4*>(copies)
                        + (size_t)s * NCHUNK * SLICE4 + j4;
    #pragma unroll 4
    for (int c = 0; c < NCHUNK; ++c) {
        const ushort4 v = base[(size_t)c * SLICE4];
        ax += bf2f(v.x); ay += bf2f(v.y); az += bf2f(v.z); aw += bf2f(v.w);
    }

    auto act = [](float x) -> int {
        const float a1 = (x  > 0.0f) ? x  : 0.1f * x;
        const float r2 = 16.0f * a1;
        const float a2 = (r2 > 0.0f) ? r2 : 0.1f * r2;
        return (int)(10.0f * a2);
    };

    int4 o;
    o.x = act(ax); o.y = act(ay); o.z = act(az); o.w = act(aw);
    reinterpret_cast<int4*>(out)[i4] = o;
}

extern "C" void kernel_launch(void* const* d_in, const int* in_sizes, int n_in,
                              void* d_out, int out_size, void* d_ws, size_t ws_size,
                              hipStream_t stream)
{
    const float* feat     = (const float*)d_in[0];
    const int*   edge_src = (const int*)d_in[1];
    const int*   edge_dst = (const int*)d_in[2];
    int*         out      = (int*)d_out;

    float* rowsum          = (float*)d_ws;                          // 400 KB
    unsigned short* val    = (unsigned short*)(rowsum + N_NODES);   // 6.4 MB
    unsigned short* copies = val + N_EDGES;                         // 16 MB

    // Kernel 1: 32 threads per node
    {
        const int threads = 256;
        const long long total = (long long)N_NODES * 32;
        const int blocks = (int)((total + threads - 1) / threads);
        rowsum_kernel<<<blocks, threads, 0, stream>>>(feat, rowsum);
    }

    // Kernel 2: phase-1 gather, 3125 blocks x 256 x 4 edges (exact tile)
    gather_kernel<<<N_EDGES / (256 * 4), 256, 0, stream>>>(edge_src, rowsum, val);

    // Kernel 3: phase-2 streaming scatter, 240 blocks, XCD-sibling swizzled
    scatter2_kernel<<<N_SLICES * NCHUNK, TPB, 0, stream>>>(edge_dst, val, copies);

    // Kernel 4: fused reduce + activations + int cast
    {
        const int threads = 256;
        const int blocks = (N_NODES / 4 + threads - 1) / threads;
        reduce_final_kernel<<<blocks, threads, 0, stream>>>(copies, out);
    }
}

// Round 10
// 58.187 us; speedup vs baseline: 1.0535x; 1.0535x over previous
//
#include <hip/hip_runtime.h>

#define N_NODES  100000
#define N_EDGES  3200000
#define D_FEAT   128

// ---- gather phase (LDS-staged table) ----
#define G_TPB    1024
#define G_EPT    8
#define G_CHUNK  (G_TPB * G_EPT)                       // 8192 edges/block
#define G_GRID   ((N_EDGES + G_CHUNK - 1) / G_CHUNK)   // 391
#define SRC_SLICE 25000                                // 4 passes x 50 KB LDS
#define N_SRC_SLICES 4

// ---- scatter phase (dst-sliced LDS accumulators) ----
#define SLICE    33344
#define SLICE4   (SLICE / 4)
#define N_SLICES 3
#define NCHUNK   80
#define EPB      40000          // N_EDGES / NCHUNK
#define S_TPB    1024
#define S_STRIDE (S_TPB * 8)

__device__ __forceinline__ unsigned short f2bf(float f) {
    union { float f; unsigned u; } c; c.f = f;
    unsigned r = c.u + 0x7FFFu + ((c.u >> 16) & 1u);   // round-nearest-even
    return (unsigned short)(r >> 16);
}
__device__ __forceinline__ float bf2f(unsigned short h) {
    union { unsigned u; float f; } c; c.u = ((unsigned)h) << 16; return c.f;
}

// ---------------------------------------------------------------------------
// Kernel 1: per-node feature row-sum -> bf16 table (only the gather reads it).
// ---------------------------------------------------------------------------
__global__ void __launch_bounds__(256) rowsum_kernel(
    const float* __restrict__ feat,
    unsigned short* __restrict__ rowsum_bf)
{
    const int gid = (int)(blockIdx.x * blockDim.x + threadIdx.x);
    const int row = gid >> 5;
    const int sub = gid & 31;
    if (row >= N_NODES) return;

    const float4 v = reinterpret_cast<const float4*>(
        feat + (size_t)row * D_FEAT)[sub];
    float s = (v.x + v.y) + (v.z + v.w);

    #pragma unroll
    for (int off = 16; off > 0; off >>= 1)
        s += __shfl_xor(s, off, 64);

    if (sub == 0) rowsum_bf[row] = f2bf(s);
}

// ---------------------------------------------------------------------------
// Kernel 2: LDS-staged gather. The bf16 rowsum table is staged into LDS in
// 4 passes of 25000 nodes (50 KB); each thread holds its 8 src indices in
// REGISTERS across passes and fills vals via ds_read (no L1-miss/MSHR path).
// Every thread participates in staging/barriers (no early return).
// ---------------------------------------------------------------------------
__global__ void __launch_bounds__(G_TPB) gather_kernel(
    const int* __restrict__ edge_src,
    const unsigned short* __restrict__ rowsum_bf,
    unsigned short* __restrict__ val)
{
    __shared__ unsigned short tbl[SRC_SLICE];   // 50 KB

    const int tid  = (int)threadIdx.x;
    const int base = (int)blockIdx.x * G_CHUNK + tid * G_EPT;
    // N_EDGES % 8 == 0 and base is 8-aligned -> thread fully valid or not
    const bool v = (base + G_EPT) <= N_EDGES;

    int4 s0 = {0,0,0,0}, s1 = {0,0,0,0};
    if (v) {
        s0 = *reinterpret_cast<const int4*>(edge_src + base);
        s1 = *reinterpret_cast<const int4*>(edge_src + base + 4);
    }

    unsigned short w0 = 0, w1 = 0, w2 = 0, w3 = 0;
    unsigned short w4 = 0, w5 = 0, w6 = 0, w7 = 0;

    #pragma unroll
    for (int p = 0; p < N_SRC_SLICES; ++p) {
        const int lo = p * SRC_SLICE;

        if (p > 0) __syncthreads();             // prior pass's reads done
        // stage slice p: 6250 x 8B coalesced
        for (int i = tid; i < SRC_SLICE / 4; i += G_TPB)
            reinterpret_cast<uint2*>(tbl)[i] =
                reinterpret_cast<const uint2*>(rowsum_bf + lo)[i];
        __syncthreads();

        #define GATHER1(S, W) { const unsigned j = (unsigned)((S) - lo); \
                                if (j < SRC_SLICE) W = tbl[j]; }
        GATHER1(s0.x, w0) GATHER1(s0.y, w1) GATHER1(s0.z, w2) GATHER1(s0.w, w3)
        GATHER1(s1.x, w4) GATHER1(s1.y, w5) GATHER1(s1.z, w6) GATHER1(s1.w, w7)
        #undef GATHER1
    }

    if (v) {
        ushort4 o0; o0.x = w0; o0.y = w1; o0.z = w2; o0.w = w3;
        ushort4 o1; o1.x = w4; o1.y = w5; o1.z = w6; o1.w = w7;
        *reinterpret_cast<ushort4*>(val + base)     = o0;
        *reinterpret_cast<ushort4*>(val + base + 4) = o1;
    }
}

// ---------------------------------------------------------------------------
// Kernel 3: streaming scatter (r9's scatter2, unchanged). Reads dst[]+val[]
// (no random global loads), masked ds_add into the LDS slice, bf16 flush.
// XCD-sibling swizzle: the 3 tier-siblings of a chunk share one XCD's L2.
// ---------------------------------------------------------------------------
__global__ void __launch_bounds__(S_TPB) scatter2_kernel(
    const int* __restrict__ edge_dst,
    const unsigned short* __restrict__ val,
    unsigned short* __restrict__ copies)
{
    __shared__ float lds[SLICE];

    const int tid = (int)threadIdx.x;
    const int bid = (int)blockIdx.x;
    const int g   = bid / 24;
    const int r   = bid % 24;
    const int xcd = r & 7;
    const int s   = r >> 3;               // slice (0..2)
    const int b   = g * 8 + xcd;          // chunk (0..79)
    const int lo  = s * SLICE;
    const unsigned len = (unsigned)((N_NODES - lo < SLICE) ? (N_NODES - lo) : SLICE);

    float4 z; z.x = z.y = z.z = z.w = 0.0f;
    for (int i = tid; i < SLICE4; i += S_TPB)
        reinterpret_cast<float4*>(lds)[i] = z;
    __syncthreads();

    const int begin = b * EPB;
    const int end   = begin + EPB;

    int e = begin + tid * 8;
    bool v = (e < end);

    int4 d0, d1; ushort4 w01, w23;
    if (v) {
        d0  = *(const int4*)(edge_dst + e);
        d1  = *(const int4*)(edge_dst + e + 4);
        w01 = *(const ushort4*)(val + e);
        w23 = *(const ushort4*)(val + e + 4);
    }

    while (v) {
        const int en = e + S_STRIDE;
        const bool vn = (en < end);
        int4 nd0, nd1; ushort4 nw01, nw23;
        if (vn) {
            nd0  = *(const int4*)(edge_dst + en);
            nd1  = *(const int4*)(edge_dst + en + 4);
            nw01 = *(const ushort4*)(val + en);
            nw23 = *(const ushort4*)(val + en + 4);
        }

        const unsigned j0 = (unsigned)(d0.x - lo);
        const unsigned j1 = (unsigned)(d0.y - lo);
        const unsigned j2 = (unsigned)(d0.z - lo);
        const unsigned j3 = (unsigned)(d0.w - lo);
        const unsigned j4 = (unsigned)(d1.x - lo);
        const unsigned j5 = (unsigned)(d1.y - lo);
        const unsigned j6 = (unsigned)(d1.z - lo);
        const unsigned j7 = (unsigned)(d1.w - lo);

        if (j0 < len) atomicAdd(&lds[j0], bf2f(w01.x));
        if (j1 < len) atomicAdd(&lds[j1], bf2f(w01.y));
        if (j2 < len) atomicAdd(&lds[j2], bf2f(w01.z));
        if (j3 < len) atomicAdd(&lds[j3], bf2f(w01.w));
        if (j4 < len) atomicAdd(&lds[j4], bf2f(w23.x));
        if (j5 < len) atomicAdd(&lds[j5], bf2f(w23.y));
        if (j6 < len) atomicAdd(&lds[j6], bf2f(w23.z));
        if (j7 < len) atomicAdd(&lds[j7], bf2f(w23.w));

        e = en; v = vn;
        d0 = nd0; d1 = nd1; w01 = nw01; w23 = nw23;
    }
    __syncthreads();

    unsigned short* __restrict__ dstp = copies + ((size_t)s * NCHUNK + b) * SLICE;
    const int len4 = (int)len >> 2;
    for (int i = tid; i < len4; i += S_TPB) {
        const float4 vv = reinterpret_cast<const float4*>(lds)[i];
        ushort4 o;
        o.x = f2bf(vv.x); o.y = f2bf(vv.y); o.z = f2bf(vv.z); o.w = f2bf(vv.w);
        reinterpret_cast<ushort4*>(dstp)[i] = o;
    }
}

// ---------------------------------------------------------------------------
// Kernel 4: reduce the NCHUNK bf16 copies per slice + activations + int cast.
// ---------------------------------------------------------------------------
__global__ void __launch_bounds__(256) reduce_final_kernel(
    const unsigned short* __restrict__ copies,
    int* __restrict__ out)
{
    const int i4 = (int)(blockIdx.x * blockDim.x + threadIdx.x);
    if (i4 >= N_NODES / 4) return;

    const int s  = (i4 >= 2 * SLICE4) ? 2 : (i4 >= SLICE4 ? 1 : 0);
    const int j4 = i4 - s * SLICE4;

    float ax = 0.0f, ay = 0.0f, az = 0.0f, aw = 0.0f;
    const ushort4* base = reinterpret_cast<const ushort4*>(copies)
                        + (size_t)s * NCHUNK * SLICE4 + j4;
    #pragma unroll 4
    for (int c = 0; c < NCHUNK; ++c) {
        const ushort4 v = base[(size_t)c * SLICE4];
        ax += bf2f(v.x); ay += bf2f(v.y); az += bf2f(v.z); aw += bf2f(v.w);
    }

    auto act = [](float x) -> int {
        const float a1 = (x  > 0.0f) ? x  : 0.1f * x;
        const float r2 = 16.0f * a1;
        const float a2 = (r2 > 0.0f) ? r2 : 0.1f * r2;
        return (int)(10.0f * a2);
    };

    int4 o;
    o.x = act(ax); o.y = act(ay); o.z = act(az); o.w = act(aw);
    reinterpret_cast<int4*>(out)[i4] = o;
}

extern "C" void kernel_launch(void* const* d_in, const int* in_sizes, int n_in,
                              void* d_out, int out_size, void* d_ws, size_t ws_size,
                              hipStream_t stream)
{
    const float* feat     = (const float*)d_in[0];
    const int*   edge_src = (const int*)d_in[1];
    const int*   edge_dst = (const int*)d_in[2];
    int*         out      = (int*)d_out;

    unsigned short* rowsum_bf = (unsigned short*)d_ws;                 // 200 KB (pad to 256 KB)
    unsigned short* val       = (unsigned short*)((char*)d_ws + (256 << 10)); // 6.4 MB
    unsigned short* copies    = val + N_EDGES;                         // 16 MB

    // Kernel 1: 32 threads per node -> bf16 rowsum table
    {
        const int threads = 256;
        const long long total = (long long)N_NODES * 32;
        const int blocks = (int)((total + threads - 1) / threads);
        rowsum_kernel<<<blocks, threads, 0, stream>>>(feat, rowsum_bf);
    }

    // Kernel 2: LDS-staged gather (391 blocks, 50 KB LDS, 4 passes)
    gather_kernel<<<G_GRID, G_TPB, 0, stream>>>(edge_src, rowsum_bf, val);

    // Kernel 3: streaming scatter, 240 blocks, XCD-sibling swizzled
    scatter2_kernel<<<N_SLICES * NCHUNK, S_TPB, 0, stream>>>(edge_dst, val, copies);

    // Kernel 4: fused reduce + activations + int cast
    {
        const int threads = 256;
        const int blocks = (N_NODES / 4 + threads - 1) / threads;
        reduce_final_kernel<<<blocks, threads, 0, stream>>>(copies, out);
    }
}